// Round 1
// baseline (265.650 us; speedup 1.0000x reference)
//
#include <hip/hip_runtime.h>
#include <hip/hip_bf16.h>
#include <stdint.h>

// ---------- common types / helpers ----------
typedef __attribute__((ext_vector_type(8))) short short8;   // 8 bf16 = 4 VGPR (MFMA A/B frag)
typedef __attribute__((ext_vector_type(4))) float f32x4;    // MFMA C/D frag
typedef __attribute__((ext_vector_type(4))) float f4;
typedef __attribute__((ext_vector_type(4))) short s4;

typedef __attribute__((address_space(1))) const void gvoid_t;
typedef __attribute__((address_space(3))) void lvoid_t;

__device__ __forceinline__ void gload_lds16(const void* g, void* l) {
  __builtin_amdgcn_global_load_lds((gvoid_t*)g, (lvoid_t*)l, 16, 0, 0);
}

__device__ __forceinline__ ushort f2b(float f) {  // f32 -> bf16 RNE
  union { float f; uint32_t u; } v; v.f = f;
  return (ushort)((v.u + 0x7fffu + ((v.u >> 16) & 1u)) >> 16);
}
__device__ __forceinline__ float b2f(ushort b) {
  union { uint32_t u; float f; } v; v.u = ((uint32_t)b) << 16;
  return v.f;
}

// ---------- problem constants ----------
// B=2 T=16 S=256 D_MODEL=1536 HEADS=16 GROUPS=4 HEAD_DIM=96
// rows = B*T*S = 8192, QKV_OUT = 2304

// ---------- f32 -> bf16 cast kernel ----------
__global__ void cvt_kernel(const float* __restrict__ in, ushort* __restrict__ out, int n4) {
  int i = blockIdx.x * 256 + threadIdx.x;
  if (i < n4) {
    f4 v = ((const f4*)in)[i];
    s4 o;
    o.x = (short)f2b(v.x); o.y = (short)f2b(v.y);
    o.z = (short)f2b(v.z); o.w = (short)f2b(v.w);
    ((s4*)out)[i] = o;
  }
}

// ---------- bf16 GEMM: C[M,N] = A[M,K] @ B[N,K]^T  (m97-style 128x128 tile) ----------
template <typename OutT>
__global__ __launch_bounds__(256) void gemm_bt(const ushort* __restrict__ A,
                                               const ushort* __restrict__ B,
                                               OutT* __restrict__ C,
                                               int M, int N, int K) {
  __shared__ ushort As[128 * 32];
  __shared__ ushort Bs[128 * 32];
  const int tid = threadIdx.x;
  const int lane = tid & 63;
  const int wave = tid >> 6;       // 0..3
  const int wr = wave >> 1, wc = wave & 1;
  const int bm = blockIdx.x, bn = blockIdx.y;

  const ushort* Ag = A + (size_t)bm * 128 * K;
  const ushort* Bg = B + (size_t)bn * 128 * K;

  // staging: chunk c covers tile row c>>2, k-subchunk (c&3)*8 (8 bf16 = 16B)
  const int c0 = tid, c1 = tid + 256;
  const int ar0 = c0 >> 2, ak0 = (c0 & 3) * 8;
  const int ar1 = c1 >> 2, ak1 = (c1 & 3) * 8;
  char* AsB = (char*)As + wave * 1024;   // wave-uniform LDS dest
  char* BsB = (char*)Bs + wave * 1024;

  const int r16 = lane & 15, kh = lane >> 4;
  f32x4 acc[4][4] = {};

  for (int kt = 0; kt < K; kt += 32) {
    gload_lds16(Ag + (size_t)ar0 * K + kt + ak0, AsB);
    gload_lds16(Ag + (size_t)ar1 * K + kt + ak1, AsB + 4096);
    gload_lds16(Bg + (size_t)ar0 * K + kt + ak0, BsB);
    gload_lds16(Bg + (size_t)ar1 * K + kt + ak1, BsB + 4096);
    __syncthreads();
    short8 af[4], bfr[4];
#pragma unroll
    for (int m = 0; m < 4; ++m)
      af[m] = *(const short8*)(As + (wr * 64 + m * 16 + r16) * 32 + kh * 8);
#pragma unroll
    for (int n = 0; n < 4; ++n)
      bfr[n] = *(const short8*)(Bs + (wc * 64 + n * 16 + r16) * 32 + kh * 8);
#pragma unroll
    for (int m = 0; m < 4; ++m)
#pragma unroll
      for (int n = 0; n < 4; ++n)
        acc[m][n] = __builtin_amdgcn_mfma_f32_16x16x32_bf16(af[m], bfr[n], acc[m][n], 0, 0, 0);
    __syncthreads();
  }

  const int rowb = bm * 128 + wr * 64;
  const int colb = bn * 128 + wc * 64;
#pragma unroll
  for (int m = 0; m < 4; ++m)
#pragma unroll
    for (int n = 0; n < 4; ++n)
#pragma unroll
      for (int r = 0; r < 4; ++r) {
        int row = rowb + m * 16 + kh * 4 + r;
        int col = colb + n * 16 + r16;
        float val = acc[m][n][r];
        if constexpr (sizeof(OutT) == 2) C[(size_t)row * N + col] = f2b(val);
        else                             C[(size_t)row * N + col] = val;
      }
}

// ---------- RoPE(3D) + rearrange ----------
// qkv: [8192][2304] bf16.  Outputs:
//   Qo: [32][16][256][96], Ko: [32][4][256][96], Vt: [32][4][96][256]  (all bf16)
__global__ void rope_kernel(const ushort* __restrict__ qkv,
                            ushort* __restrict__ Qo, ushort* __restrict__ Ko,
                            ushort* __restrict__ Vt) {
  const int UNITS = 1344;  // 16*48 q-pairs + 4*48 k-pairs + 4*96 v-elems
  int idx = blockIdx.x * 256 + threadIdx.x;
  if (idx >= 8192 * UNITS) return;
  int row = idx / UNITS;
  int unit = idx - row * UNITS;
  int bt = row >> 8, s = row & 255;
  const ushort* qr = qkv + (size_t)row * 2304;
  if (unit < 960) {
    int head, p;
    size_t srcoff;
    ushort* dst;
    if (unit < 768) {            // q
      head = unit / 48; p = unit % 48;
      srcoff = (size_t)head * 96;
      dst = Qo + ((size_t)(bt * 16 + head) * 256 + s) * 96;
    } else {                     // k
      int u = unit - 768;
      head = u / 48; p = u % 48;
      srcoff = 1536 + (size_t)head * 96;
      dst = Ko + ((size_t)(bt * 4 + head) * 256 + s) * 96;
    }
    int seg = p >> 4, i = p & 15;
    int pos = (seg == 0) ? (bt & 15) : ((seg == 1) ? (s >> 4) : (s & 15));
    float inv_freq = expf(-(float)i * 0.5756462732485115f);  // ln(10000)/16
    float ang = (float)pos * inv_freq;
    float c = cosf(ang), sn = sinf(ang);
    float x1 = b2f(qr[srcoff + seg * 32 + i]);
    float x2 = b2f(qr[srcoff + seg * 32 + i + 16]);
    dst[seg * 32 + i]      = f2b(x1 * c - x2 * sn);
    dst[seg * 32 + i + 16] = f2b(x1 * sn + x2 * c);
  } else {                       // v -> transposed copy
    int u = unit - 960;          // 0..383
    int g = u / 96, d = u - g * 96;
    Vt[((size_t)(bt * 4 + g) * 96 + d) * 256 + s] = qr[1920 + (size_t)g * 96 + d];
  }
}

// ---------- attention: one block = (bt, head, 64 q-rows), 4 waves x 16 q-rows ----------
__global__ __launch_bounds__(256) void attn_kernel(
    const ushort* __restrict__ Q,   // [32][16][256][96]
    const ushort* __restrict__ Kr,  // [32][4][256][96]
    const ushort* __restrict__ Vt,  // [32][4][96][256]
    const int* __restrict__ mask,   // [32][256]
    ushort* __restrict__ Out) {     // [8192][1536] bf16 (row = bt*256+s, col = h*96+d)
  __shared__ ushort Pl[4][16][256];  // per-wave P tile (32 KiB)

  int bid = blockIdx.x;
  int qt = bid & 3;
  int h = (bid >> 2) & 15;
  int bt = bid >> 6;
  int g = h >> 2;
  int lane = threadIdx.x & 63, wave = threadIdx.x >> 6;
  int r16 = lane & 15, kh = lane >> 4;
  int qbase = qt * 64 + wave * 16;

  const ushort* Qp = Q + ((size_t)(bt * 16 + h) * 256 + qbase) * 96;
  const ushort* Kp = Kr + (size_t)(bt * 4 + g) * 256 * 96;
  const ushort* Vp = Vt + (size_t)(bt * 4 + g) * 96 * 256;

  // Q fragments (A operand): row = r16, k = kc*32 + kh*8 .. +8
  short8 qf[3];
#pragma unroll
  for (int kc = 0; kc < 3; ++kc)
    qf[kc] = *(const short8*)(Qp + (size_t)r16 * 96 + kc * 32 + kh * 8);

  // scores: 16 key-tiles of 16
  f32x4 sc[16];
#pragma unroll
  for (int f = 0; f < 16; ++f) {
    f32x4 a = {0.f, 0.f, 0.f, 0.f};
#pragma unroll
    for (int kc = 0; kc < 3; ++kc) {
      short8 kf = *(const short8*)(Kp + (size_t)(f * 16 + r16) * 96 + kc * 32 + kh * 8);
      a = __builtin_amdgcn_mfma_f32_16x16x32_bf16(qf[kc], kf, a, 0, 0, 0);
    }
    sc[f] = a;
  }

  // scale + mask (key = f*16 + r16, same for all 4 regs of a lane)
  const float scale = 0.10206207261596575f;  // 1/sqrt(96)
#pragma unroll
  for (int f = 0; f < 16; ++f) {
    int m = mask[bt * 256 + f * 16 + r16];
    float4 dummy;
#pragma unroll
    for (int r = 0; r < 4; ++r)
      sc[f][r] = m ? sc[f][r] * scale : -1.0e9f;
    (void)dummy;
  }

  // softmax per q-row (row = kh*4 + reg); reduce across 16 frags + 16 lanes of group
  float inv[4];
#pragma unroll
  for (int reg = 0; reg < 4; ++reg) {
    float mx = -3.0e38f;
#pragma unroll
    for (int f = 0; f < 16; ++f) mx = fmaxf(mx, sc[f][reg]);
    for (int o = 8; o >= 1; o >>= 1) mx = fmaxf(mx, __shfl_xor(mx, o, 64));
    float sm = 0.f;
#pragma unroll
    for (int f = 0; f < 16; ++f) {
      float p = __expf(sc[f][reg] - mx);
      sc[f][reg] = p;
      sm += p;
    }
    for (int o = 8; o >= 1; o >>= 1) sm += __shfl_xor(sm, o, 64);
    inv[reg] = 1.0f / sm;
  }

  // P -> LDS (transpose to A-layout for PV)
#pragma unroll
  for (int f = 0; f < 16; ++f)
#pragma unroll
    for (int reg = 0; reg < 4; ++reg)
      Pl[wave][kh * 4 + reg][f * 16 + r16] = f2b(sc[f][reg]);

  // PV: out(16x96) = P(16x256) @ V(256x96); B from Vt[d][s]
  short8 pf[8];
#pragma unroll
  for (int kc = 0; kc < 8; ++kc)
    pf[kc] = *(const short8*)(&Pl[wave][r16][kc * 32 + kh * 8]);

  f32x4 oacc[6] = {};
#pragma unroll
  for (int dt = 0; dt < 6; ++dt) {
#pragma unroll
    for (int kc = 0; kc < 8; ++kc) {
      short8 vf = *(const short8*)(Vp + (size_t)(dt * 16 + r16) * 256 + kc * 32 + kh * 8);
      oacc[dt] = __builtin_amdgcn_mfma_f32_16x16x32_bf16(pf[kc], vf, oacc[dt], 0, 0, 0);
    }
  }

  // write out (normalize rows by inv[reg])
#pragma unroll
  for (int dt = 0; dt < 6; ++dt)
#pragma unroll
    for (int reg = 0; reg < 4; ++reg) {
      int srow = qbase + kh * 4 + reg;
      size_t orow = (size_t)bt * 256 + srow;
      Out[orow * 1536 + h * 96 + dt * 16 + r16] = f2b(oacc[dt][reg] * inv[reg]);
    }
}

// ---------- launch ----------
extern "C" void kernel_launch(void* const* d_in, const int* in_sizes, int n_in,
                              void* d_out, int out_size, void* d_ws, size_t ws_size,
                              hipStream_t stream) {
  const float* x     = (const float*)d_in[0];   // [2][16][256][1536]
  const int* pmask   = (const int*)d_in[1];     // [32][256]
  const float* w_qkv = (const float*)d_in[2];   // [2304][1536]
  const float* w_o   = (const float*)d_in[3];   // [1536][1536]
  float* out = (float*)d_out;                   // [8192][1536] f32

  char* ws = (char*)d_ws;
  ushort* Xb  = (ushort*)(ws + 0);          // 8192x1536 bf16   (25165824 B)
  ushort* Wq  = (ushort*)(ws + 25165824);   // 2304x1536 bf16   ( 7077888 B)
  ushort* Wo  = (ushort*)(ws + 32243712);   // 1536x1536 bf16   ( 4718592 B)
  ushort* QKV = (ushort*)(ws + 36962304);   // 8192x2304 bf16   (37748736 B)
  ushort* Qr  = (ushort*)(ws + 74711040);   // 32x16x256x96     (25165824 B)
  ushort* Kr  = (ushort*)(ws + 99876864);   // 32x4x256x96      ( 6291456 B)
  ushort* Vt  = (ushort*)(ws + 106168320);  // 32x4x96x256      ( 6291456 B)
  ushort* Attn = Xb;                        // reuse Xb slot after gemm1

  cvt_kernel<<<3145728 / 256, 256, 0, stream>>>(x, Xb, 3145728);      // 12582912/4
  cvt_kernel<<<884736 / 256, 256, 0, stream>>>(w_qkv, Wq, 884736);    // 3538944/4
  cvt_kernel<<<589824 / 256, 256, 0, stream>>>(w_o, Wo, 589824);      // 2359296/4

  gemm_bt<ushort><<<dim3(64, 18), 256, 0, stream>>>(Xb, Wq, QKV, 8192, 2304, 1536);

  rope_kernel<<<(8192 * 1344) / 256, 256, 0, stream>>>(QKV, Qr, Kr, Vt);

  attn_kernel<<<2048, 256, 0, stream>>>(Qr, Kr, Vt, pmask, Attn);

  gemm_bt<float><<<dim3(64, 12), 256, 0, stream>>>(Attn, Wo, out, 8192, 1536, 1536);
}

// Round 2
// 238.354 us; speedup vs baseline: 1.1145x; 1.1145x over previous
//
#include <hip/hip_runtime.h>
#include <hip/hip_bf16.h>
#include <stdint.h>

// ---------- common types / helpers ----------
typedef __attribute__((ext_vector_type(8))) short short8;   // 8 bf16 = 4 VGPR (MFMA A/B frag)
typedef __attribute__((ext_vector_type(4))) float f32x4;    // MFMA C/D frag
typedef __attribute__((ext_vector_type(4))) float f4;
typedef __attribute__((ext_vector_type(4))) short s4;

typedef __attribute__((address_space(1))) const void gvoid_t;
typedef __attribute__((address_space(3))) void lvoid_t;

__device__ __forceinline__ void gload_lds16(const void* g, void* l) {
  __builtin_amdgcn_global_load_lds((gvoid_t*)g, (lvoid_t*)l, 16, 0, 0);
}

__device__ __forceinline__ ushort f2b(float f) {  // f32 -> bf16 RNE
  union { float f; uint32_t u; } v; v.f = f;
  return (ushort)((v.u + 0x7fffu + ((v.u >> 16) & 1u)) >> 16);
}
__device__ __forceinline__ float b2f(ushort b) {
  union { uint32_t u; float f; } v; v.u = ((uint32_t)b) << 16;
  return v.f;
}

template <int N> __device__ __forceinline__ void wait_vmcnt();
template <> __device__ __forceinline__ void wait_vmcnt<0>() { asm volatile("s_waitcnt vmcnt(0)" ::: "memory"); }
template <> __device__ __forceinline__ void wait_vmcnt<1>() { asm volatile("s_waitcnt vmcnt(1)" ::: "memory"); }
template <> __device__ __forceinline__ void wait_vmcnt<2>() { asm volatile("s_waitcnt vmcnt(2)" ::: "memory"); }

__device__ __forceinline__ void wait_lgkm0() {
  asm volatile("s_waitcnt lgkmcnt(0)" ::: "memory");
  __builtin_amdgcn_sched_barrier(0);   // rule #18: keep MFMA below the wait
}

// Stage ROWS rows (row stride = 64 bf16 in LDS, linear) from global (leading dim ldg).
// Pre-swizzled source: LDS[row][c] gets Global[row][c ^ (row&7)] so swizzled reads are conflict-free.
template <int ROWS>
__device__ __forceinline__ void stage_rows(const ushort* __restrict__ g, int ldg,
                                           ushort* lds, int w, int l, int sc) {
#pragma unroll
  for (int i = 0; i < ROWS / 64; ++i)
    gload_lds16(g + (size_t)(i * 64 + w * 8 + (l >> 3)) * ldg + sc * 8,
                lds + i * 4096 + w * 512);
  if constexpr ((ROWS % 64) != 0) {
    if (w < (ROWS % 64) / 8)
      gload_lds16(g + (size_t)((ROWS / 64) * 64 + w * 8 + (l >> 3)) * ldg + sc * 8,
                  lds + (ROWS / 64) * 4096 + w * 512);
  }
}

// ---------- f32 -> bf16 cast kernel ----------
__global__ void cvt_kernel(const float* __restrict__ in, ushort* __restrict__ out, int n4) {
  int i = blockIdx.x * 256 + threadIdx.x;
  if (i < n4) {
    f4 v = ((const f4*)in)[i];
    s4 o;
    o.x = (short)f2b(v.x); o.y = (short)f2b(v.y);
    o.z = (short)f2b(v.z); o.w = (short)f2b(v.w);
    ((s4*)out)[i] = o;
  }
}

// ---------- 8-phase-style bf16 GEMM: C[M,N] = A[M,K] @ B[N,K]^T ----------
// BM=256 fixed, BN in {288,192}; grid = (M/256)*(N/BN) = 256 blocks exactly (tail-free).
// 8 waves as 4M x 2N (wave tile 64 x BN/2). BK=64, double-buffered LDS, per-phase raw
// barriers + counted vmcnt; XOR-swizzled LDS (involution, pre-swizzled global source).
template <int BN, typename OutT>
__global__ __launch_bounds__(512, 2) void gemm8(const ushort* __restrict__ A,
                                                const ushort* __restrict__ B,
                                                OutT* __restrict__ C,
                                                int N, int K) {
  constexpr int NF = BN / 32;       // n-frags per wave
  constexpr int NH0 = (NF + 1) / 2; // first n-group
  constexpr int NH1 = NF - NH0;     // second n-group
  constexpr int RB = BN / 2;        // B half-tile rows
  constexpr int VMC = RB / 64;      // min per-wave gloads of one B-half stage

  __shared__ ushort As[2][256 * 64];
  __shared__ ushort Bs[2][BN * 64];

  const int tid = threadIdx.x;
  const int l = tid & 63, w = tid >> 6;
  const int wr = w >> 1, wc = w & 1;          // 4M x 2N
  const int r16 = l & 15, kh = l >> 4;
  const int sc = (l & 7) ^ (l >> 3);          // pre-swizzled source chunk

  const int bn = blockIdx.x & 7;              // one N-stripe per XCD (GN==8)
  const int bm = blockIdx.x >> 3;
  const ushort* Ag = A + (size_t)bm * 256 * K;
  const ushort* Bg = B + (size_t)bn * BN * K;
  const int NT = K >> 6;

  // prologue: B0(0),B1(0),A0(0),A1(0) -> buf0 ; B0(1) -> buf1
  stage_rows<RB >(Bg,                    K, &Bs[0][0],        w, l, sc);
  stage_rows<RB >(Bg + (size_t)RB * K,   K, &Bs[0][RB * 64],  w, l, sc);
  stage_rows<128>(Ag,                    K, &As[0][0],        w, l, sc);
  stage_rows<128>(Ag + (size_t)128 * K,  K, &As[0][128 * 64], w, l, sc);
  stage_rows<RB >(Bg + 64,               K, &Bs[1][0],        w, l, sc);
  wait_vmcnt<VMC>();
  __builtin_amdgcn_s_barrier();

  f32x4 acc[4][NF] = {};
  short8 afr[2][2], bfr[NH0][2];

  for (int u = 0; u < NT; ++u) {
    const int p = u & 1;
    const ushort* Asb = &As[p][0];
    const ushort* Bsb = &Bs[p][0];
    ushort* Asn = &As[p ^ 1][0];
    ushort* Bsn = &Bs[p ^ 1][0];
    const int kt1 = (u + 1) << 6, kt2 = (u + 2) << 6;
    const bool st1 = (u + 1 < NT), st2 = (u + 2 < NT);

    // ---- phase 0: read B(nh0)+A(mh0); stage A0(u+1), B1(u+1); MFMA mh0 x nh0
#pragma unroll
    for (int n = 0; n < NH0; ++n)
#pragma unroll
      for (int ks = 0; ks < 2; ++ks)
        bfr[n][ks] = *(const short8*)(Bsb + (wc * RB + n * 16 + r16) * 64 +
                                      (((ks * 4 + kh) ^ (r16 & 7)) * 8));
#pragma unroll
    for (int mm = 0; mm < 2; ++mm)
#pragma unroll
      for (int ks = 0; ks < 2; ++ks)
        afr[mm][ks] = *(const short8*)(Asb + (wr * 64 + mm * 16 + r16) * 64 +
                                       (((ks * 4 + kh) ^ (r16 & 7)) * 8));
    if (st1) {
      stage_rows<128>(Ag + kt1,                     K, Asn,           w, l, sc);
      stage_rows<RB >(Bg + (size_t)RB * K + kt1,    K, Bsn + RB * 64, w, l, sc);
    }
    __builtin_amdgcn_s_barrier();
    wait_lgkm0();
    __builtin_amdgcn_s_setprio(1);
#pragma unroll
    for (int mm = 0; mm < 2; ++mm)
#pragma unroll
      for (int n = 0; n < NH0; ++n)
#pragma unroll
        for (int ks = 0; ks < 2; ++ks)
          acc[mm][n] = __builtin_amdgcn_mfma_f32_16x16x32_bf16(afr[mm][ks], bfr[n][ks], acc[mm][n], 0, 0, 0);
    __builtin_amdgcn_s_setprio(0);
    __builtin_amdgcn_s_barrier();

    // ---- phase 1: read A(mh1); stage A1(u+1); MFMA mh1 x nh0
#pragma unroll
    for (int mm = 0; mm < 2; ++mm)
#pragma unroll
      for (int ks = 0; ks < 2; ++ks)
        afr[mm][ks] = *(const short8*)(Asb + (wr * 64 + (2 + mm) * 16 + r16) * 64 +
                                       (((ks * 4 + kh) ^ (r16 & 7)) * 8));
    if (st1) stage_rows<128>(Ag + (size_t)128 * K + kt1, K, Asn + 128 * 64, w, l, sc);
    __builtin_amdgcn_s_barrier();
    wait_lgkm0();
    __builtin_amdgcn_s_setprio(1);
#pragma unroll
    for (int mm = 0; mm < 2; ++mm)
#pragma unroll
      for (int n = 0; n < NH0; ++n)
#pragma unroll
        for (int ks = 0; ks < 2; ++ks)
          acc[2 + mm][n] = __builtin_amdgcn_mfma_f32_16x16x32_bf16(afr[mm][ks], bfr[n][ks], acc[2 + mm][n], 0, 0, 0);
    __builtin_amdgcn_s_setprio(0);
    __builtin_amdgcn_s_barrier();

    // ---- phase 2: read B(nh1); MFMA mh1 x nh1 (afr still holds mh1)
#pragma unroll
    for (int n = 0; n < NH1; ++n)
#pragma unroll
      for (int ks = 0; ks < 2; ++ks)
        bfr[n][ks] = *(const short8*)(Bsb + (wc * RB + (NH0 + n) * 16 + r16) * 64 +
                                      (((ks * 4 + kh) ^ (r16 & 7)) * 8));
    __builtin_amdgcn_s_barrier();
    wait_lgkm0();
    __builtin_amdgcn_s_setprio(1);
#pragma unroll
    for (int mm = 0; mm < 2; ++mm)
#pragma unroll
      for (int n = 0; n < NH1; ++n)
#pragma unroll
        for (int ks = 0; ks < 2; ++ks)
          acc[2 + mm][NH0 + n] = __builtin_amdgcn_mfma_f32_16x16x32_bf16(afr[mm][ks], bfr[n][ks], acc[2 + mm][NH0 + n], 0, 0, 0);
    __builtin_amdgcn_s_setprio(0);
    __builtin_amdgcn_s_barrier();

    // ---- phase 3: re-read A(mh0); stage B0(u+2); counted vmcnt; MFMA mh0 x nh1
#pragma unroll
    for (int mm = 0; mm < 2; ++mm)
#pragma unroll
      for (int ks = 0; ks < 2; ++ks)
        afr[mm][ks] = *(const short8*)(Asb + (wr * 64 + mm * 16 + r16) * 64 +
                                       (((ks * 4 + kh) ^ (r16 & 7)) * 8));
    if (st2) stage_rows<RB>(Bg + kt2, K, &Bs[p][0], w, l, sc);
    if (u < NT - 2) wait_vmcnt<VMC>(); else wait_vmcnt<0>();
    __builtin_amdgcn_s_barrier();
    wait_lgkm0();
    __builtin_amdgcn_s_setprio(1);
#pragma unroll
    for (int mm = 0; mm < 2; ++mm)
#pragma unroll
      for (int n = 0; n < NH1; ++n)
#pragma unroll
        for (int ks = 0; ks < 2; ++ks)
          acc[mm][NH0 + n] = __builtin_amdgcn_mfma_f32_16x16x32_bf16(afr[mm][ks], bfr[n][ks], acc[mm][NH0 + n], 0, 0, 0);
    __builtin_amdgcn_s_setprio(0);
    __builtin_amdgcn_s_barrier();
  }

  // epilogue: D col = lane&15, row = (lane>>4)*4 + reg
  const int rowb = bm * 256 + wr * 64;
  const int colb = bn * BN + wc * RB;
#pragma unroll
  for (int m = 0; m < 4; ++m)
#pragma unroll
    for (int n = 0; n < NF; ++n)
#pragma unroll
      for (int r = 0; r < 4; ++r) {
        int row = rowb + m * 16 + kh * 4 + r;
        int col = colb + n * 16 + r16;
        float val = acc[m][n][r];
        if constexpr (sizeof(OutT) == 2) C[(size_t)row * N + col] = f2b(val);
        else                             C[(size_t)row * N + col] = val;
      }
}

// ---------- RoPE(3D) + rearrange ----------
__global__ void rope_kernel(const ushort* __restrict__ qkv,
                            ushort* __restrict__ Qo, ushort* __restrict__ Ko,
                            ushort* __restrict__ Vt) {
  const int UNITS = 1344;  // 16*48 q-pairs + 4*48 k-pairs + 4*96 v-elems
  int idx = blockIdx.x * 256 + threadIdx.x;
  if (idx >= 8192 * UNITS) return;
  int row = idx / UNITS;
  int unit = idx - row * UNITS;
  int bt = row >> 8, s = row & 255;
  const ushort* qr = qkv + (size_t)row * 2304;
  if (unit < 960) {
    int head, p;
    size_t srcoff;
    ushort* dst;
    if (unit < 768) {            // q
      head = unit / 48; p = unit % 48;
      srcoff = (size_t)head * 96;
      dst = Qo + ((size_t)(bt * 16 + head) * 256 + s) * 96;
    } else {                     // k
      int u = unit - 768;
      head = u / 48; p = u % 48;
      srcoff = 1536 + (size_t)head * 96;
      dst = Ko + ((size_t)(bt * 4 + head) * 256 + s) * 96;
    }
    int seg = p >> 4, i = p & 15;
    int pos = (seg == 0) ? (bt & 15) : ((seg == 1) ? (s >> 4) : (s & 15));
    float inv_freq = expf(-(float)i * 0.5756462732485115f);  // ln(10000)/16
    float ang = (float)pos * inv_freq;
    float c = cosf(ang), sn = sinf(ang);
    float x1 = b2f(qr[srcoff + seg * 32 + i]);
    float x2 = b2f(qr[srcoff + seg * 32 + i + 16]);
    dst[seg * 32 + i]      = f2b(x1 * c - x2 * sn);
    dst[seg * 32 + i + 16] = f2b(x1 * sn + x2 * c);
  } else {                       // v -> transposed copy
    int u = unit - 960;          // 0..383
    int g = u / 96, d = u - g * 96;
    Vt[((size_t)(bt * 4 + g) * 96 + d) * 256 + s] = qr[1920 + (size_t)g * 96 + d];
  }
}

// ---------- attention: one block = (bt, head, 64 q-rows), 4 waves x 16 q-rows ----------
__global__ __launch_bounds__(256) void attn_kernel(
    const ushort* __restrict__ Q,   // [32][16][256][96]
    const ushort* __restrict__ Kr,  // [32][4][256][96]
    const ushort* __restrict__ Vt,  // [32][4][96][256]
    const int* __restrict__ mask,   // [32][256]
    ushort* __restrict__ Out) {     // [8192][1536] bf16
  __shared__ ushort Pl[4][16][256];

  int bid = blockIdx.x;
  int qt = bid & 3;
  int h = (bid >> 2) & 15;
  int bt = bid >> 6;
  int g = h >> 2;
  int lane = threadIdx.x & 63, wave = threadIdx.x >> 6;
  int r16 = lane & 15, kh = lane >> 4;
  int qbase = qt * 64 + wave * 16;

  const ushort* Qp = Q + ((size_t)(bt * 16 + h) * 256 + qbase) * 96;
  const ushort* Kp = Kr + (size_t)(bt * 4 + g) * 256 * 96;
  const ushort* Vp = Vt + (size_t)(bt * 4 + g) * 96 * 256;

  short8 qf[3];
#pragma unroll
  for (int kc = 0; kc < 3; ++kc)
    qf[kc] = *(const short8*)(Qp + (size_t)r16 * 96 + kc * 32 + kh * 8);

  f32x4 sc[16];
#pragma unroll
  for (int f = 0; f < 16; ++f) {
    f32x4 a = {0.f, 0.f, 0.f, 0.f};
#pragma unroll
    for (int kc = 0; kc < 3; ++kc) {
      short8 kf = *(const short8*)(Kp + (size_t)(f * 16 + r16) * 96 + kc * 32 + kh * 8);
      a = __builtin_amdgcn_mfma_f32_16x16x32_bf16(qf[kc], kf, a, 0, 0, 0);
    }
    sc[f] = a;
  }

  const float scale = 0.10206207261596575f;  // 1/sqrt(96)
#pragma unroll
  for (int f = 0; f < 16; ++f) {
    int m = mask[bt * 256 + f * 16 + r16];
#pragma unroll
    for (int r = 0; r < 4; ++r)
      sc[f][r] = m ? sc[f][r] * scale : -1.0e9f;
  }

  float inv[4];
#pragma unroll
  for (int reg = 0; reg < 4; ++reg) {
    float mx = -3.0e38f;
#pragma unroll
    for (int f = 0; f < 16; ++f) mx = fmaxf(mx, sc[f][reg]);
    for (int o = 8; o >= 1; o >>= 1) mx = fmaxf(mx, __shfl_xor(mx, o, 64));
    float sm = 0.f;
#pragma unroll
    for (int f = 0; f < 16; ++f) {
      float pp = __expf(sc[f][reg] - mx);
      sc[f][reg] = pp;
      sm += pp;
    }
    for (int o = 8; o >= 1; o >>= 1) sm += __shfl_xor(sm, o, 64);
    inv[reg] = 1.0f / sm;
  }

#pragma unroll
  for (int f = 0; f < 16; ++f)
#pragma unroll
    for (int reg = 0; reg < 4; ++reg)
      Pl[wave][kh * 4 + reg][f * 16 + r16] = f2b(sc[f][reg]);

  short8 pf[8];
#pragma unroll
  for (int kc = 0; kc < 8; ++kc)
    pf[kc] = *(const short8*)(&Pl[wave][r16][kc * 32 + kh * 8]);

  f32x4 oacc[6] = {};
#pragma unroll
  for (int dt = 0; dt < 6; ++dt) {
#pragma unroll
    for (int kc = 0; kc < 8; ++kc) {
      short8 vf = *(const short8*)(Vp + (size_t)(dt * 16 + r16) * 256 + kc * 32 + kh * 8);
      oacc[dt] = __builtin_amdgcn_mfma_f32_16x16x32_bf16(pf[kc], vf, oacc[dt], 0, 0, 0);
    }
  }

#pragma unroll
  for (int dt = 0; dt < 6; ++dt)
#pragma unroll
    for (int reg = 0; reg < 4; ++reg) {
      int srow = qbase + kh * 4 + reg;
      size_t orow = (size_t)bt * 256 + srow;
      Out[orow * 1536 + h * 96 + dt * 16 + r16] = f2b(oacc[dt][reg] * inv[reg]);
    }
}

// ---------- launch ----------
extern "C" void kernel_launch(void* const* d_in, const int* in_sizes, int n_in,
                              void* d_out, int out_size, void* d_ws, size_t ws_size,
                              hipStream_t stream) {
  const float* x     = (const float*)d_in[0];   // [2][16][256][1536]
  const int* pmask   = (const int*)d_in[1];     // [32][256]
  const float* w_qkv = (const float*)d_in[2];   // [2304][1536]
  const float* w_o   = (const float*)d_in[3];   // [1536][1536]
  float* out = (float*)d_out;                   // [8192][1536] f32

  char* ws = (char*)d_ws;
  ushort* Xb  = (ushort*)(ws + 0);          // 8192x1536 bf16
  ushort* Wq  = (ushort*)(ws + 25165824);   // 2304x1536 bf16
  ushort* Wo  = (ushort*)(ws + 32243712);   // 1536x1536 bf16
  ushort* QKV = (ushort*)(ws + 36962304);   // 8192x2304 bf16
  ushort* Qr  = (ushort*)(ws + 74711040);   // 32x16x256x96
  ushort* Kr  = (ushort*)(ws + 99876864);   // 32x4x256x96
  ushort* Vt  = (ushort*)(ws + 106168320);  // 32x4x96x256
  ushort* Attn = Xb;                        // reuse Xb slot after gemm1

  cvt_kernel<<<3145728 / 256, 256, 0, stream>>>(x, Xb, 3145728);
  cvt_kernel<<<884736 / 256, 256, 0, stream>>>(w_qkv, Wq, 884736);
  cvt_kernel<<<589824 / 256, 256, 0, stream>>>(w_o, Wo, 589824);

  gemm8<288, ushort><<<256, 512, 0, stream>>>(Xb, Wq, QKV, 2304, 1536);

  rope_kernel<<<(8192 * 1344) / 256, 256, 0, stream>>>(QKV, Qr, Kr, Vt);

  attn_kernel<<<2048, 256, 0, stream>>>(Qr, Kr, Vt, pmask, Attn);

  gemm8<192, float><<<256, 512, 0, stream>>>(Attn, Wo, out, 1536, 1536);
}

// Round 3
// 192.422 us; speedup vs baseline: 1.3806x; 1.2387x over previous
//
#include <hip/hip_runtime.h>
#include <hip/hip_bf16.h>
#include <stdint.h>

// ---------- common types / helpers ----------
typedef __attribute__((ext_vector_type(8))) short short8;   // 8 bf16 = 4 VGPR (MFMA A/B frag)
typedef __attribute__((ext_vector_type(4))) float f32x4;    // MFMA C/D frag
typedef __attribute__((ext_vector_type(4))) float f4;
typedef __attribute__((ext_vector_type(4))) short s4;

typedef __attribute__((address_space(1))) const void gvoid_t;
typedef __attribute__((address_space(3))) void lvoid_t;

__device__ __forceinline__ void gload_lds16(const void* g, void* l) {
  __builtin_amdgcn_global_load_lds((gvoid_t*)g, (lvoid_t*)l, 16, 0, 0);
}

__device__ __forceinline__ ushort f2b(float f) {  // f32 -> bf16 RNE
  union { float f; uint32_t u; } v; v.f = f;
  return (ushort)((v.u + 0x7fffu + ((v.u >> 16) & 1u)) >> 16);
}
__device__ __forceinline__ float b2f(ushort b) {
  union { uint32_t u; float f; } v; v.u = ((uint32_t)b) << 16;
  return v.f;
}

template <int N> __device__ __forceinline__ void wait_vmcnt();
template <> __device__ __forceinline__ void wait_vmcnt<0>() { asm volatile("s_waitcnt vmcnt(0)" ::: "memory"); }
template <> __device__ __forceinline__ void wait_vmcnt<1>() { asm volatile("s_waitcnt vmcnt(1)" ::: "memory"); }
template <> __device__ __forceinline__ void wait_vmcnt<2>() { asm volatile("s_waitcnt vmcnt(2)" ::: "memory"); }

__device__ __forceinline__ void wait_lgkm0() {
  asm volatile("s_waitcnt lgkmcnt(0)" ::: "memory");
  __builtin_amdgcn_sched_barrier(0);   // rule #18: keep MFMA below the wait
}

// Stage ROWS rows (row stride = 64 bf16 in LDS, linear) from global (leading dim ldg).
template <int ROWS>
__device__ __forceinline__ void stage_rows(const ushort* __restrict__ g, int ldg,
                                           ushort* lds, int w, int l, int sc) {
#pragma unroll
  for (int i = 0; i < ROWS / 64; ++i)
    gload_lds16(g + (size_t)(i * 64 + w * 8 + (l >> 3)) * ldg + sc * 8,
                lds + i * 4096 + w * 512);
  if constexpr ((ROWS % 64) != 0) {
    if (w < (ROWS % 64) / 8)
      gload_lds16(g + (size_t)((ROWS / 64) * 64 + w * 8 + (l >> 3)) * ldg + sc * 8,
                  lds + (ROWS / 64) * 4096 + w * 512);
  }
}

// ---------- f32 -> bf16 cast kernel ----------
__global__ void cvt_kernel(const float* __restrict__ in, ushort* __restrict__ out, int n4) {
  int i = blockIdx.x * 256 + threadIdx.x;
  if (i < n4) {
    f4 v = ((const f4*)in)[i];
    s4 o;
    o.x = (short)f2b(v.x); o.y = (short)f2b(v.y);
    o.z = (short)f2b(v.z); o.w = (short)f2b(v.w);
    ((s4*)out)[i] = o;
  }
}

// ---------- 8-phase-style bf16 GEMM: C[M,N] = A[M,K] @ B[N,K]^T ----------
template <int BN, typename OutT>
__global__ __launch_bounds__(512, 2) void gemm8(const ushort* __restrict__ A,
                                                const ushort* __restrict__ B,
                                                OutT* __restrict__ C,
                                                int N, int K) {
  constexpr int NF = BN / 32;
  constexpr int NH0 = (NF + 1) / 2;
  constexpr int NH1 = NF - NH0;
  constexpr int RB = BN / 2;
  constexpr int VMC = RB / 64;

  __shared__ ushort As[2][256 * 64];
  __shared__ ushort Bs[2][BN * 64];

  const int tid = threadIdx.x;
  const int l = tid & 63, w = tid >> 6;
  const int wr = w >> 1, wc = w & 1;
  const int r16 = l & 15, kh = l >> 4;
  const int sc = (l & 7) ^ (l >> 3);

  const int bn = blockIdx.x & 7;
  const int bm = blockIdx.x >> 3;
  const ushort* Ag = A + (size_t)bm * 256 * K;
  const ushort* Bg = B + (size_t)bn * BN * K;
  const int NT = K >> 6;

  stage_rows<RB >(Bg,                    K, &Bs[0][0],        w, l, sc);
  stage_rows<RB >(Bg + (size_t)RB * K,   K, &Bs[0][RB * 64],  w, l, sc);
  stage_rows<128>(Ag,                    K, &As[0][0],        w, l, sc);
  stage_rows<128>(Ag + (size_t)128 * K,  K, &As[0][128 * 64], w, l, sc);
  stage_rows<RB >(Bg + 64,               K, &Bs[1][0],        w, l, sc);
  wait_vmcnt<VMC>();
  __builtin_amdgcn_s_barrier();

  f32x4 acc[4][NF] = {};
  short8 afr[2][2], bfr[NH0][2];

  for (int u = 0; u < NT; ++u) {
    const int p = u & 1;
    const ushort* Asb = &As[p][0];
    const ushort* Bsb = &Bs[p][0];
    ushort* Asn = &As[p ^ 1][0];
    ushort* Bsn = &Bs[p ^ 1][0];
    const int kt1 = (u + 1) << 6, kt2 = (u + 2) << 6;
    const bool st1 = (u + 1 < NT), st2 = (u + 2 < NT);

#pragma unroll
    for (int n = 0; n < NH0; ++n)
#pragma unroll
      for (int ks = 0; ks < 2; ++ks)
        bfr[n][ks] = *(const short8*)(Bsb + (wc * RB + n * 16 + r16) * 64 +
                                      (((ks * 4 + kh) ^ (r16 & 7)) * 8));
#pragma unroll
    for (int mm = 0; mm < 2; ++mm)
#pragma unroll
      for (int ks = 0; ks < 2; ++ks)
        afr[mm][ks] = *(const short8*)(Asb + (wr * 64 + mm * 16 + r16) * 64 +
                                       (((ks * 4 + kh) ^ (r16 & 7)) * 8));
    if (st1) {
      stage_rows<128>(Ag + kt1,                     K, Asn,           w, l, sc);
      stage_rows<RB >(Bg + (size_t)RB * K + kt1,    K, Bsn + RB * 64, w, l, sc);
    }
    __builtin_amdgcn_s_barrier();
    wait_lgkm0();
    __builtin_amdgcn_s_setprio(1);
#pragma unroll
    for (int mm = 0; mm < 2; ++mm)
#pragma unroll
      for (int n = 0; n < NH0; ++n)
#pragma unroll
        for (int ks = 0; ks < 2; ++ks)
          acc[mm][n] = __builtin_amdgcn_mfma_f32_16x16x32_bf16(afr[mm][ks], bfr[n][ks], acc[mm][n], 0, 0, 0);
    __builtin_amdgcn_s_setprio(0);
    __builtin_amdgcn_s_barrier();

#pragma unroll
    for (int mm = 0; mm < 2; ++mm)
#pragma unroll
      for (int ks = 0; ks < 2; ++ks)
        afr[mm][ks] = *(const short8*)(Asb + (wr * 64 + (2 + mm) * 16 + r16) * 64 +
                                       (((ks * 4 + kh) ^ (r16 & 7)) * 8));
    if (st1) stage_rows<128>(Ag + (size_t)128 * K + kt1, K, Asn + 128 * 64, w, l, sc);
    __builtin_amdgcn_s_barrier();
    wait_lgkm0();
    __builtin_amdgcn_s_setprio(1);
#pragma unroll
    for (int mm = 0; mm < 2; ++mm)
#pragma unroll
      for (int n = 0; n < NH0; ++n)
#pragma unroll
        for (int ks = 0; ks < 2; ++ks)
          acc[2 + mm][n] = __builtin_amdgcn_mfma_f32_16x16x32_bf16(afr[mm][ks], bfr[n][ks], acc[2 + mm][n], 0, 0, 0);
    __builtin_amdgcn_s_setprio(0);
    __builtin_amdgcn_s_barrier();

#pragma unroll
    for (int n = 0; n < NH1; ++n)
#pragma unroll
      for (int ks = 0; ks < 2; ++ks)
        bfr[n][ks] = *(const short8*)(Bsb + (wc * RB + (NH0 + n) * 16 + r16) * 64 +
                                      (((ks * 4 + kh) ^ (r16 & 7)) * 8));
    __builtin_amdgcn_s_barrier();
    wait_lgkm0();
    __builtin_amdgcn_s_setprio(1);
#pragma unroll
    for (int mm = 0; mm < 2; ++mm)
#pragma unroll
      for (int n = 0; n < NH1; ++n)
#pragma unroll
        for (int ks = 0; ks < 2; ++ks)
          acc[2 + mm][NH0 + n] = __builtin_amdgcn_mfma_f32_16x16x32_bf16(afr[mm][ks], bfr[n][ks], acc[2 + mm][NH0 + n], 0, 0, 0);
    __builtin_amdgcn_s_setprio(0);
    __builtin_amdgcn_s_barrier();

#pragma unroll
    for (int mm = 0; mm < 2; ++mm)
#pragma unroll
      for (int ks = 0; ks < 2; ++ks)
        afr[mm][ks] = *(const short8*)(Asb + (wr * 64 + mm * 16 + r16) * 64 +
                                       (((ks * 4 + kh) ^ (r16 & 7)) * 8));
    if (st2) stage_rows<RB>(Bg + kt2, K, &Bs[p][0], w, l, sc);
    if (u < NT - 2) wait_vmcnt<VMC>(); else wait_vmcnt<0>();
    __builtin_amdgcn_s_barrier();
    wait_lgkm0();
    __builtin_amdgcn_s_setprio(1);
#pragma unroll
    for (int mm = 0; mm < 2; ++mm)
#pragma unroll
      for (int n = 0; n < NH1; ++n)
#pragma unroll
        for (int ks = 0; ks < 2; ++ks)
          acc[mm][NH0 + n] = __builtin_amdgcn_mfma_f32_16x16x32_bf16(afr[mm][ks], bfr[n][ks], acc[mm][NH0 + n], 0, 0, 0);
    __builtin_amdgcn_s_setprio(0);
    __builtin_amdgcn_s_barrier();
  }

  const int rowb = bm * 256 + wr * 64;
  const int colb = bn * BN + wc * RB;
#pragma unroll
  for (int m = 0; m < 4; ++m)
#pragma unroll
    for (int n = 0; n < NF; ++n)
#pragma unroll
      for (int r = 0; r < 4; ++r) {
        int row = rowb + m * 16 + kh * 4 + r;
        int col = colb + n * 16 + r16;
        float val = acc[m][n][r];
        if constexpr (sizeof(OutT) == 2) C[(size_t)row * N + col] = f2b(val);
        else                             C[(size_t)row * N + col] = val;
      }
}

// ---------- RoPE(3D) + rearrange ----------
__global__ void rope_kernel(const ushort* __restrict__ qkv,
                            ushort* __restrict__ Qo, ushort* __restrict__ Ko,
                            ushort* __restrict__ Vt) {
  const int UNITS = 1344;
  int idx = blockIdx.x * 256 + threadIdx.x;
  if (idx >= 8192 * UNITS) return;
  int row = idx / UNITS;
  int unit = idx - row * UNITS;
  int bt = row >> 8, s = row & 255;
  const ushort* qr = qkv + (size_t)row * 2304;
  if (unit < 960) {
    int head, p;
    size_t srcoff;
    ushort* dst;
    if (unit < 768) {            // q
      head = unit / 48; p = unit % 48;
      srcoff = (size_t)head * 96;
      dst = Qo + ((size_t)(bt * 16 + head) * 256 + s) * 96;
    } else {                     // k
      int u = unit - 768;
      head = u / 48; p = u % 48;
      srcoff = 1536 + (size_t)head * 96;
      dst = Ko + ((size_t)(bt * 4 + head) * 256 + s) * 96;
    }
    int seg = p >> 4, i = p & 15;
    int pos = (seg == 0) ? (bt & 15) : ((seg == 1) ? (s >> 4) : (s & 15));
    float inv_freq = __expf(-(float)i * 0.5756462732485115f);  // ln(10000)/16
    float ang = (float)pos * inv_freq;
    float sn, c;
    __sincosf(ang, &sn, &c);
    float x1 = b2f(qr[srcoff + seg * 32 + i]);
    float x2 = b2f(qr[srcoff + seg * 32 + i + 16]);
    dst[seg * 32 + i]      = f2b(x1 * c - x2 * sn);
    dst[seg * 32 + i + 16] = f2b(x1 * sn + x2 * c);
  } else {                       // v -> transposed copy
    int u = unit - 960;
    int g = u / 96, d = u - g * 96;
    Vt[((size_t)(bt * 4 + g) * 96 + d) * 256 + s] = qr[1920 + (size_t)g * 96 + d];
  }
}

// ---------- attention v2: one block per (bt, g, qhalf); K/V staged once in LDS ----------
// 256 blocks x 512 threads (8 waves). wave = (head within group)*2 + qchunk.
// Each wave: 64 q-rows as 2 m-pairs of 32; K/V LDS frags shared across the pair.
__global__ __launch_bounds__(512, 2) void attn2_kernel(
    const ushort* __restrict__ Q,   // [32][16][256][96]
    const ushort* __restrict__ Kr,  // [32][4][256][96]
    const ushort* __restrict__ Vt,  // [32][4][96][256]
    const int* __restrict__ mask,   // [32][256]
    ushort* __restrict__ Out) {     // [8192][1536] bf16
  __shared__ ushort Ks[256 * 104];  // K padded stride 104 (53.0 KB)
  __shared__ ushort Vs[96 * 264];   // V^T padded stride 264 (50.7 KB)
  __shared__ ushort Ps[8][16 * 136];// per-wave P chunk, padded stride 136 (34.8 KB)
  __shared__ float Mb[256];         // additive mask bias (1 KB)

  const int b = blockIdx.x;
  const int qt = b & 1;             // q half (128 rows)
  const int g = (b >> 1) & 3;
  const int bt = b >> 3;
  const int t = threadIdx.x;
  const int l = t & 63, w = t >> 6;
  const int r16 = l & 15, kh = l >> 4;
  const int h = g * 4 + (w >> 1);   // head
  const int qc = w & 1;             // 64-row chunk within the 128-row half

  const ushort* Kp = Kr + (size_t)(bt * 4 + g) * 256 * 96;
  const ushort* Vp = Vt + (size_t)(bt * 4 + g) * 96 * 256;

  // ---- stage K [256][96] -> Ks [256][104]
  {
    int r = t >> 1, ch = t & 1;
#pragma unroll
    for (int j = 0; j < 6; ++j)
      *(short8*)(&Ks[r * 104 + ch * 48 + j * 8]) =
          *(const short8*)(Kp + (size_t)r * 96 + ch * 48 + j * 8);
  }
  // ---- stage V^T [96][256] -> Vs [96][264]
#pragma unroll
  for (int i = 0; i < 6; ++i) {
    int c = t + i * 512;
    int vr = c >> 5, vc = c & 31;
    *(short8*)(&Vs[vr * 264 + vc * 8]) =
        *(const short8*)(Vp + (size_t)vr * 256 + vc * 8);
  }
  if (t < 256) Mb[t] = mask[bt * 256 + t] ? 0.0f : -1.0e9f;
  __syncthreads();

  const ushort* Qp = Q + ((size_t)(bt * 16 + h) * 256 + qt * 128 + qc * 64) * 96;
  ushort* Pw = &Ps[w][0];
  const float scale = 0.10206207261596575f;  // 1/sqrt(96)

#pragma unroll
  for (int mp = 0; mp < 2; ++mp) {
    const int qb = mp * 32;

    short8 qfA[3], qfB[3];
#pragma unroll
    for (int kc = 0; kc < 3; ++kc) {
      qfA[kc] = *(const short8*)(Qp + (size_t)(qb + r16) * 96 + kc * 32 + kh * 8);
      qfB[kc] = *(const short8*)(Qp + (size_t)(qb + 16 + r16) * 96 + kc * 32 + kh * 8);
    }

    // ---- QK^T: K frag shared across the two m-frags
    f32x4 scA[16] = {}, scB[16] = {};
#pragma unroll
    for (int f = 0; f < 16; ++f) {
#pragma unroll
      for (int kc = 0; kc < 3; ++kc) {
        short8 kf = *(const short8*)(&Ks[(f * 16 + r16) * 104 + kc * 32 + kh * 8]);
        scA[f] = __builtin_amdgcn_mfma_f32_16x16x32_bf16(qfA[kc], kf, scA[f], 0, 0, 0);
        scB[f] = __builtin_amdgcn_mfma_f32_16x16x32_bf16(qfB[kc], kf, scB[f], 0, 0, 0);
      }
    }

    // ---- scale + mask bias
#pragma unroll
    for (int f = 0; f < 16; ++f) {
      float mb = Mb[f * 16 + r16];
#pragma unroll
      for (int r = 0; r < 4; ++r) {
        scA[f][r] = scA[f][r] * scale + mb;
        scB[f][r] = scB[f][r] * scale + mb;
      }
    }

    // ---- softmax (per q-row = kh*4+reg; keys across f and 16-lane group)
    float invA[4], invB[4];
#pragma unroll
    for (int reg = 0; reg < 4; ++reg) {
      float mxA = -3.0e38f, mxB = -3.0e38f;
#pragma unroll
      for (int f = 0; f < 16; ++f) { mxA = fmaxf(mxA, scA[f][reg]); mxB = fmaxf(mxB, scB[f][reg]); }
      for (int o = 8; o >= 1; o >>= 1) { mxA = fmaxf(mxA, __shfl_xor(mxA, o, 64)); mxB = fmaxf(mxB, __shfl_xor(mxB, o, 64)); }
      float smA = 0.f, smB = 0.f;
#pragma unroll
      for (int f = 0; f < 16; ++f) {
        float pA = __expf(scA[f][reg] - mxA);
        float pB = __expf(scB[f][reg] - mxB);
        scA[f][reg] = pA; scB[f][reg] = pB;
        smA += pA; smB += pB;
      }
      for (int o = 8; o >= 1; o >>= 1) { smA += __shfl_xor(smA, o, 64); smB += __shfl_xor(smB, o, 64); }
      invA[reg] = 1.0f / smA;
      invB[reg] = 1.0f / smB;
    }

    // ---- P transpose via per-wave LDS chunks (16 x 128, padded 136)
    short8 pfA[8], pfB[8];
#pragma unroll
    for (int ck = 0; ck < 2; ++ck) {                 // m0: chunk0, chunk1
#pragma unroll
      for (int f = 0; f < 8; ++f)
#pragma unroll
        for (int reg = 0; reg < 4; ++reg)
          Pw[(kh * 4 + reg) * 136 + f * 16 + r16] = f2b(scA[ck * 8 + f][reg]);
#pragma unroll
      for (int kc = 0; kc < 4; ++kc)
        pfA[ck * 4 + kc] = *(const short8*)(&Pw[r16 * 136 + kc * 32 + kh * 8]);
    }
#pragma unroll
    for (int ck = 0; ck < 2; ++ck) {                 // m1
#pragma unroll
      for (int f = 0; f < 8; ++f)
#pragma unroll
        for (int reg = 0; reg < 4; ++reg)
          Pw[(kh * 4 + reg) * 136 + f * 16 + r16] = f2b(scB[ck * 8 + f][reg]);
#pragma unroll
      for (int kc = 0; kc < 4; ++kc)
        pfB[ck * 4 + kc] = *(const short8*)(&Pw[r16 * 136 + kc * 32 + kh * 8]);
    }

    // ---- PV: V frag shared across the two m-frags
    f32x4 oA[6] = {}, oB[6] = {};
#pragma unroll
    for (int dt = 0; dt < 6; ++dt) {
#pragma unroll
      for (int kc = 0; kc < 8; ++kc) {
        short8 vf = *(const short8*)(&Vs[(dt * 16 + r16) * 264 + kc * 32 + kh * 8]);
        oA[dt] = __builtin_amdgcn_mfma_f32_16x16x32_bf16(pfA[kc], vf, oA[dt], 0, 0, 0);
        oB[dt] = __builtin_amdgcn_mfma_f32_16x16x32_bf16(pfB[kc], vf, oB[dt], 0, 0, 0);
      }
    }

    // ---- write out
    const int rbase = bt * 256 + qt * 128 + qc * 64 + qb;
#pragma unroll
    for (int dt = 0; dt < 6; ++dt)
#pragma unroll
      for (int reg = 0; reg < 4; ++reg) {
        int col = h * 96 + dt * 16 + r16;
        Out[(size_t)(rbase + kh * 4 + reg) * 1536 + col]      = f2b(oA[dt][reg] * invA[reg]);
        Out[(size_t)(rbase + 16 + kh * 4 + reg) * 1536 + col] = f2b(oB[dt][reg] * invB[reg]);
      }
  }
}

// ---------- launch ----------
extern "C" void kernel_launch(void* const* d_in, const int* in_sizes, int n_in,
                              void* d_out, int out_size, void* d_ws, size_t ws_size,
                              hipStream_t stream) {
  const float* x     = (const float*)d_in[0];   // [2][16][256][1536]
  const int* pmask   = (const int*)d_in[1];     // [32][256]
  const float* w_qkv = (const float*)d_in[2];   // [2304][1536]
  const float* w_o   = (const float*)d_in[3];   // [1536][1536]
  float* out = (float*)d_out;                   // [8192][1536] f32

  char* ws = (char*)d_ws;
  ushort* Xb  = (ushort*)(ws + 0);          // 8192x1536 bf16
  ushort* Wq  = (ushort*)(ws + 25165824);   // 2304x1536 bf16
  ushort* Wo  = (ushort*)(ws + 32243712);   // 1536x1536 bf16
  ushort* QKV = (ushort*)(ws + 36962304);   // 8192x2304 bf16
  ushort* Qr  = (ushort*)(ws + 74711040);   // 32x16x256x96
  ushort* Kr  = (ushort*)(ws + 99876864);   // 32x4x256x96
  ushort* Vt  = (ushort*)(ws + 106168320);  // 32x4x96x256
  ushort* Attn = Xb;                        // reuse Xb slot after gemm1

  cvt_kernel<<<3145728 / 256, 256, 0, stream>>>(x, Xb, 3145728);
  cvt_kernel<<<884736 / 256, 256, 0, stream>>>(w_qkv, Wq, 884736);
  cvt_kernel<<<589824 / 256, 256, 0, stream>>>(w_o, Wo, 589824);

  gemm8<288, ushort><<<256, 512, 0, stream>>>(Xb, Wq, QKV, 2304, 1536);

  rope_kernel<<<(8192 * 1344) / 256, 256, 0, stream>>>(QKV, Qr, Kr, Vt);

  attn2_kernel<<<256, 512, 0, stream>>>(Qr, Kr, Vt, pmask, Attn);

  gemm8<192, float><<<256, 512, 0, stream>>>(Attn, Wo, out, 1536, 1536);
}

// Round 4
// 175.822 us; speedup vs baseline: 1.5109x; 1.0944x over previous
//
#include <hip/hip_runtime.h>
#include <hip/hip_bf16.h>
#include <stdint.h>

// ---------- common types / helpers ----------
typedef __attribute__((ext_vector_type(8))) short short8;   // 8 bf16 = 4 VGPR (MFMA A/B frag)
typedef __attribute__((ext_vector_type(4))) float f32x4;    // MFMA C/D frag
typedef __attribute__((ext_vector_type(4))) float f4;
typedef __attribute__((ext_vector_type(4))) short s4;

typedef __attribute__((address_space(1))) const void gvoid_t;
typedef __attribute__((address_space(3))) void lvoid_t;

__device__ __forceinline__ void gload_lds16(const void* g, void* l) {
  __builtin_amdgcn_global_load_lds((gvoid_t*)g, (lvoid_t*)l, 16, 0, 0);
}

__device__ __forceinline__ ushort f2b(float f) {  // f32 -> bf16 RNE
  union { float f; uint32_t u; } v; v.f = f;
  return (ushort)((v.u + 0x7fffu + ((v.u >> 16) & 1u)) >> 16);
}
__device__ __forceinline__ float b2f(ushort b) {
  union { uint32_t u; float f; } v; v.u = ((uint32_t)b) << 16;
  return v.f;
}

template <int N> __device__ __forceinline__ void wait_vmcnt();
template <> __device__ __forceinline__ void wait_vmcnt<0>() { asm volatile("s_waitcnt vmcnt(0)" ::: "memory"); }
template <> __device__ __forceinline__ void wait_vmcnt<1>() { asm volatile("s_waitcnt vmcnt(1)" ::: "memory"); }
template <> __device__ __forceinline__ void wait_vmcnt<2>() { asm volatile("s_waitcnt vmcnt(2)" ::: "memory"); }
template <> __device__ __forceinline__ void wait_vmcnt<3>() { asm volatile("s_waitcnt vmcnt(3)" ::: "memory"); }

__device__ __forceinline__ void wait_lgkm0() {
  asm volatile("s_waitcnt lgkmcnt(0)" ::: "memory");
  __builtin_amdgcn_sched_barrier(0);   // rule #18: keep MFMA below the wait
}

// Stage ROWS rows (row stride = 64 bf16 in LDS, linear) from global (leading dim ldg).
// Pre-swizzled source: LDS[row][c] gets Global[row][c ^ (row&7)] (c = 16B chunk).
template <int ROWS>
__device__ __forceinline__ void stage_rows(const ushort* __restrict__ g, int ldg,
                                           ushort* lds, int w, int l, int sc) {
#pragma unroll
  for (int i = 0; i < ROWS / 64; ++i)
    gload_lds16(g + (size_t)(i * 64 + w * 8 + (l >> 3)) * ldg + sc * 8,
                lds + i * 4096 + w * 512);
  if constexpr ((ROWS % 64) != 0) {
    if (w < (ROWS % 64) / 8)
      gload_lds16(g + (size_t)((ROWS / 64) * 64 + w * 8 + (l >> 3)) * ldg + sc * 8,
                  lds + (ROWS / 64) * 4096 + w * 512);
  }
}

// ---------- f32 -> bf16 cast kernel ----------
__global__ void cvt_kernel(const float* __restrict__ in, ushort* __restrict__ out, int n4) {
  int i = blockIdx.x * 256 + threadIdx.x;
  if (i < n4) {
    f4 v = ((const f4*)in)[i];
    s4 o;
    o.x = (short)f2b(v.x); o.y = (short)f2b(v.y);
    o.z = (short)f2b(v.z); o.w = (short)f2b(v.w);
    ((s4*)out)[i] = o;
  }
}

// ---------- bf16 GEMM v3: C[M,N] = A[M,K] @ B[N,K]^T ----------
// BM=256, BN in {288,192}; grid = 32 bm x 8 bn = 256 blocks (tail-free, 1/CU).
// XCD-owned bm chunks: xcd = bid&7 owns bm in [4*xcd, 4*xcd+4) for all bn.
// 2 barriers/K-tile, counted per-wave vmcnt leaving exactly B0(u+2) in flight.
template <int BN, typename OutT>
__global__ __launch_bounds__(512, 2) void gemm3(const ushort* __restrict__ A,
                                                const ushort* __restrict__ B,
                                                OutT* __restrict__ C,
                                                int N, int K) {
  constexpr int NF = BN / 32;           // n-frags per wave (wave tile 64 x BN/2)
  constexpr int NH0 = (NF + 1) / 2;
  constexpr int NH1 = NF - NH0;
  constexpr int RB = BN / 2;            // B half-tile rows
  constexpr int B0FULL = RB / 64;       // per-wave full stage rounds for a B half
  constexpr int B0EXTRA = (RB % 64) / 8;// first B0EXTRA waves issue one extra

  __shared__ ushort As[2][256 * 64];
  __shared__ ushort Bs[2][BN * 64];

  const int tid = threadIdx.x;
  const int l = tid & 63, w = tid >> 6;
  const int wr = w >> 1, wc = w & 1;    // 4M x 2N
  const int r16 = l & 15, kh = l >> 4;
  const int sc = (l & 7) ^ (l >> 3);    // pre-swizzled source chunk

  const int xcd = blockIdx.x & 7;
  const int ii = blockIdx.x >> 3;       // 0..31
  const int bm = xcd * 4 + (ii & 3);    // XCD owns 4 contiguous A panels
  const int bn = ii >> 2;               // 0..7
  const ushort* Ag = A + (size_t)bm * 256 * K;
  const ushort* Bg = B + (size_t)bn * BN * K;
  const int NT = K >> 6;

  // prologue: full A(0), B(0) -> buf0 ; B0(1) -> buf1 (left in flight)
  stage_rows<128>(Ag,                   K, &As[0][0],        w, l, sc);
  stage_rows<128>(Ag + (size_t)128 * K, K, &As[0][128 * 64], w, l, sc);
  stage_rows<RB >(Bg,                   K, &Bs[0][0],        w, l, sc);
  stage_rows<RB >(Bg + (size_t)RB * K,  K, &Bs[0][RB * 64],  w, l, sc);
  stage_rows<RB >(Bg + 64,              K, &Bs[1][0],        w, l, sc);
  if (B0EXTRA > 0 && w < B0EXTRA) wait_vmcnt<B0FULL + 1>(); else wait_vmcnt<B0FULL>();
  __builtin_amdgcn_s_barrier();

  f32x4 acc[4][NF] = {};
  short8 afr[4][2], bfr[NH0][2];

  for (int u = 0; u < NT; ++u) {
    const int cur = u & 1;
    const ushort* Asb = &As[cur][0];
    const ushort* Bsb = &Bs[cur][0];
    ushort* Asn = &As[cur ^ 1][0];
    ushort* Bsn = &Bs[cur ^ 1][0];
    const int kt1 = (u + 1) << 6, kt2 = (u + 2) << 6;
    const bool st1 = (u + 1 < NT), st2 = (u + 2 < NT);

    // ---- reads: B nh0 + all A; stage A(u+1), B1(u+1)
#pragma unroll
    for (int n = 0; n < NH0; ++n)
#pragma unroll
      for (int ks = 0; ks < 2; ++ks)
        bfr[n][ks] = *(const short8*)(Bsb + (wc * RB + n * 16 + r16) * 64 +
                                      (((ks * 4 + kh) ^ (r16 & 7)) * 8));
#pragma unroll
    for (int mm = 0; mm < 4; ++mm)
#pragma unroll
      for (int ks = 0; ks < 2; ++ks)
        afr[mm][ks] = *(const short8*)(Asb + (wr * 64 + mm * 16 + r16) * 64 +
                                       (((ks * 4 + kh) ^ (r16 & 7)) * 8));
    if (st1) {
      stage_rows<128>(Ag + kt1,                    K, Asn,            w, l, sc);
      stage_rows<128>(Ag + (size_t)128 * K + kt1,  K, Asn + 128 * 64, w, l, sc);
      stage_rows<RB >(Bg + (size_t)RB * K + kt1,   K, Bsn + RB * 64,  w, l, sc);
    }
    wait_lgkm0();
    __builtin_amdgcn_s_setprio(1);
#pragma unroll
    for (int mm = 0; mm < 4; ++mm)
#pragma unroll
      for (int n = 0; n < NH0; ++n)
#pragma unroll
        for (int ks = 0; ks < 2; ++ks)
          acc[mm][n] = __builtin_amdgcn_mfma_f32_16x16x32_bf16(afr[mm][ks], bfr[n][ks], acc[mm][n], 0, 0, 0);
    __builtin_amdgcn_s_setprio(0);

    // ---- reads: B nh1 (reuse bfr regs)
#pragma unroll
    for (int n = 0; n < NH1; ++n)
#pragma unroll
      for (int ks = 0; ks < 2; ++ks)
        bfr[n][ks] = *(const short8*)(Bsb + (wc * RB + (NH0 + n) * 16 + r16) * 64 +
                                      (((ks * 4 + kh) ^ (r16 & 7)) * 8));
    wait_lgkm0();
    __builtin_amdgcn_s_setprio(1);
#pragma unroll
    for (int mm = 0; mm < 4; ++mm)
#pragma unroll
      for (int n = 0; n < NH1; ++n)
#pragma unroll
        for (int ks = 0; ks < 2; ++ks)
          acc[mm][NH0 + n] = __builtin_amdgcn_mfma_f32_16x16x32_bf16(afr[mm][ks], bfr[n][ks], acc[mm][NH0 + n], 0, 0, 0);
    __builtin_amdgcn_s_setprio(0);

    // ---- alpha barrier: all B-row reads landed (lgkm0 before each MFMA cluster)
    __builtin_amdgcn_s_barrier();
    if (st2) stage_rows<RB>(Bg + kt2, K, &Bs[cur][0], w, l, sc);
    // beta wait: drain everything except B0(u+2)
    if (st2) { if (B0EXTRA > 0 && w < B0EXTRA) wait_vmcnt<B0FULL + 1>(); else wait_vmcnt<B0FULL>(); }
    else wait_vmcnt<0>();
    __builtin_amdgcn_s_barrier();
  }

  // epilogue: D col = lane&15, row = (lane>>4)*4 + reg
  const int rowb = bm * 256 + wr * 64;
  const int colb = bn * BN + wc * RB;
#pragma unroll
  for (int m = 0; m < 4; ++m)
#pragma unroll
    for (int n = 0; n < NF; ++n)
#pragma unroll
      for (int r = 0; r < 4; ++r) {
        int row = rowb + m * 16 + kh * 4 + r;
        int col = colb + n * 16 + r16;
        float val = acc[m][n][r];
        if constexpr (sizeof(OutT) == 2) C[(size_t)row * N + col] = f2b(val);
        else                             C[(size_t)row * N + col] = val;
      }
}

// ---------- RoPE(3D) + rearrange ----------
__global__ void rope_kernel(const ushort* __restrict__ qkv,
                            ushort* __restrict__ Qo, ushort* __restrict__ Ko,
                            ushort* __restrict__ Vt) {
  const int UNITS = 1344;
  int idx = blockIdx.x * 256 + threadIdx.x;
  if (idx >= 8192 * UNITS) return;
  int row = idx / UNITS;
  int unit = idx - row * UNITS;
  int bt = row >> 8, s = row & 255;
  const ushort* qr = qkv + (size_t)row * 2304;
  if (unit < 960) {
    int head, p;
    size_t srcoff;
    ushort* dst;
    if (unit < 768) {            // q
      head = unit / 48; p = unit % 48;
      srcoff = (size_t)head * 96;
      dst = Qo + ((size_t)(bt * 16 + head) * 256 + s) * 96;
    } else {                     // k
      int u = unit - 768;
      head = u / 48; p = u % 48;
      srcoff = 1536 + (size_t)head * 96;
      dst = Ko + ((size_t)(bt * 4 + head) * 256 + s) * 96;
    }
    int seg = p >> 4, i = p & 15;
    int pos = (seg == 0) ? (bt & 15) : ((seg == 1) ? (s >> 4) : (s & 15));
    float inv_freq = __expf(-(float)i * 0.5756462732485115f);  // ln(10000)/16
    float ang = (float)pos * inv_freq;
    float sn, c;
    __sincosf(ang, &sn, &c);
    float x1 = b2f(qr[srcoff + seg * 32 + i]);
    float x2 = b2f(qr[srcoff + seg * 32 + i + 16]);
    dst[seg * 32 + i]      = f2b(x1 * c - x2 * sn);
    dst[seg * 32 + i + 16] = f2b(x1 * sn + x2 * c);
  } else {                       // v -> transposed copy
    int u = unit - 960;
    int g = u / 96, d = u - g * 96;
    Vt[((size_t)(bt * 4 + g) * 96 + d) * 256 + s] = qr[1920 + (size_t)g * 96 + d];
  }
}

// ---------- attention v2: one block per (bt, g, qhalf); K/V staged once in LDS ----------
__global__ __launch_bounds__(512, 2) void attn2_kernel(
    const ushort* __restrict__ Q,   // [32][16][256][96]
    const ushort* __restrict__ Kr,  // [32][4][256][96]
    const ushort* __restrict__ Vt,  // [32][4][96][256]
    const int* __restrict__ mask,   // [32][256]
    ushort* __restrict__ Out) {     // [8192][1536] bf16
  __shared__ ushort Ks[256 * 104];
  __shared__ ushort Vs[96 * 264];
  __shared__ ushort Ps[8][16 * 136];
  __shared__ float Mb[256];

  const int b = blockIdx.x;
  const int qt = b & 1;
  const int g = (b >> 1) & 3;
  const int bt = b >> 3;
  const int t = threadIdx.x;
  const int l = t & 63, w = t >> 6;
  const int r16 = l & 15, kh = l >> 4;
  const int h = g * 4 + (w >> 1);
  const int qc = w & 1;

  const ushort* Kp = Kr + (size_t)(bt * 4 + g) * 256 * 96;
  const ushort* Vp = Vt + (size_t)(bt * 4 + g) * 96 * 256;

  {
    int r = t >> 1, ch = t & 1;
#pragma unroll
    for (int j = 0; j < 6; ++j)
      *(short8*)(&Ks[r * 104 + ch * 48 + j * 8]) =
          *(const short8*)(Kp + (size_t)r * 96 + ch * 48 + j * 8);
  }
#pragma unroll
  for (int i = 0; i < 6; ++i) {
    int c = t + i * 512;
    int vr = c >> 5, vc = c & 31;
    *(short8*)(&Vs[vr * 264 + vc * 8]) =
        *(const short8*)(Vp + (size_t)vr * 256 + vc * 8);
  }
  if (t < 256) Mb[t] = mask[bt * 256 + t] ? 0.0f : -1.0e9f;
  __syncthreads();

  const ushort* Qp = Q + ((size_t)(bt * 16 + h) * 256 + qt * 128 + qc * 64) * 96;
  ushort* Pw = &Ps[w][0];
  const float scale = 0.10206207261596575f;  // 1/sqrt(96)

#pragma unroll
  for (int mp = 0; mp < 2; ++mp) {
    const int qb = mp * 32;

    short8 qfA[3], qfB[3];
#pragma unroll
    for (int kc = 0; kc < 3; ++kc) {
      qfA[kc] = *(const short8*)(Qp + (size_t)(qb + r16) * 96 + kc * 32 + kh * 8);
      qfB[kc] = *(const short8*)(Qp + (size_t)(qb + 16 + r16) * 96 + kc * 32 + kh * 8);
    }

    f32x4 scA[16] = {}, scB[16] = {};
#pragma unroll
    for (int f = 0; f < 16; ++f) {
#pragma unroll
      for (int kc = 0; kc < 3; ++kc) {
        short8 kf = *(const short8*)(&Ks[(f * 16 + r16) * 104 + kc * 32 + kh * 8]);
        scA[f] = __builtin_amdgcn_mfma_f32_16x16x32_bf16(qfA[kc], kf, scA[f], 0, 0, 0);
        scB[f] = __builtin_amdgcn_mfma_f32_16x16x32_bf16(qfB[kc], kf, scB[f], 0, 0, 0);
      }
    }

#pragma unroll
    for (int f = 0; f < 16; ++f) {
      float mb = Mb[f * 16 + r16];
#pragma unroll
      for (int r = 0; r < 4; ++r) {
        scA[f][r] = scA[f][r] * scale + mb;
        scB[f][r] = scB[f][r] * scale + mb;
      }
    }

    float invA[4], invB[4];
#pragma unroll
    for (int reg = 0; reg < 4; ++reg) {
      float mxA = -3.0e38f, mxB = -3.0e38f;
#pragma unroll
      for (int f = 0; f < 16; ++f) { mxA = fmaxf(mxA, scA[f][reg]); mxB = fmaxf(mxB, scB[f][reg]); }
      for (int o = 8; o >= 1; o >>= 1) { mxA = fmaxf(mxA, __shfl_xor(mxA, o, 64)); mxB = fmaxf(mxB, __shfl_xor(mxB, o, 64)); }
      float smA = 0.f, smB = 0.f;
#pragma unroll
      for (int f = 0; f < 16; ++f) {
        float pA = __expf(scA[f][reg] - mxA);
        float pB = __expf(scB[f][reg] - mxB);
        scA[f][reg] = pA; scB[f][reg] = pB;
        smA += pA; smB += pB;
      }
      for (int o = 8; o >= 1; o >>= 1) { smA += __shfl_xor(smA, o, 64); smB += __shfl_xor(smB, o, 64); }
      invA[reg] = 1.0f / smA;
      invB[reg] = 1.0f / smB;
    }

    short8 pfA[8], pfB[8];
#pragma unroll
    for (int ck = 0; ck < 2; ++ck) {
#pragma unroll
      for (int f = 0; f < 8; ++f)
#pragma unroll
        for (int reg = 0; reg < 4; ++reg)
          Pw[(kh * 4 + reg) * 136 + f * 16 + r16] = f2b(scA[ck * 8 + f][reg]);
#pragma unroll
      for (int kc = 0; kc < 4; ++kc)
        pfA[ck * 4 + kc] = *(const short8*)(&Pw[r16 * 136 + kc * 32 + kh * 8]);
    }
#pragma unroll
    for (int ck = 0; ck < 2; ++ck) {
#pragma unroll
      for (int f = 0; f < 8; ++f)
#pragma unroll
        for (int reg = 0; reg < 4; ++reg)
          Pw[(kh * 4 + reg) * 136 + f * 16 + r16] = f2b(scB[ck * 8 + f][reg]);
#pragma unroll
      for (int kc = 0; kc < 4; ++kc)
        pfB[ck * 4 + kc] = *(const short8*)(&Pw[r16 * 136 + kc * 32 + kh * 8]);
    }

    f32x4 oA[6] = {}, oB[6] = {};
#pragma unroll
    for (int dt = 0; dt < 6; ++dt) {
#pragma unroll
      for (int kc = 0; kc < 8; ++kc) {
        short8 vf = *(const short8*)(&Vs[(dt * 16 + r16) * 264 + kc * 32 + kh * 8]);
        oA[dt] = __builtin_amdgcn_mfma_f32_16x16x32_bf16(pfA[kc], vf, oA[dt], 0, 0, 0);
        oB[dt] = __builtin_amdgcn_mfma_f32_16x16x32_bf16(pfB[kc], vf, oB[dt], 0, 0, 0);
      }
    }

    const int rbase = bt * 256 + qt * 128 + qc * 64 + qb;
#pragma unroll
    for (int dt = 0; dt < 6; ++dt)
#pragma unroll
      for (int reg = 0; reg < 4; ++reg) {
        int col = h * 96 + dt * 16 + r16;
        Out[(size_t)(rbase + kh * 4 + reg) * 1536 + col]      = f2b(oA[dt][reg] * invA[reg]);
        Out[(size_t)(rbase + 16 + kh * 4 + reg) * 1536 + col] = f2b(oB[dt][reg] * invB[reg]);
      }
  }
}

// ---------- launch ----------
extern "C" void kernel_launch(void* const* d_in, const int* in_sizes, int n_in,
                              void* d_out, int out_size, void* d_ws, size_t ws_size,
                              hipStream_t stream) {
  const float* x     = (const float*)d_in[0];   // [2][16][256][1536]
  const int* pmask   = (const int*)d_in[1];     // [32][256]
  const float* w_qkv = (const float*)d_in[2];   // [2304][1536]
  const float* w_o   = (const float*)d_in[3];   // [1536][1536]
  float* out = (float*)d_out;                   // [8192][1536] f32

  char* ws = (char*)d_ws;
  ushort* Xb  = (ushort*)(ws + 0);          // 8192x1536 bf16
  ushort* Wq  = (ushort*)(ws + 25165824);   // 2304x1536 bf16
  ushort* Wo  = (ushort*)(ws + 32243712);   // 1536x1536 bf16
  ushort* QKV = (ushort*)(ws + 36962304);   // 8192x2304 bf16
  ushort* Qr  = (ushort*)(ws + 74711040);   // 32x16x256x96
  ushort* Kr  = (ushort*)(ws + 99876864);   // 32x4x256x96
  ushort* Vt  = (ushort*)(ws + 106168320);  // 32x4x96x256
  ushort* Attn = Xb;                        // reuse Xb slot after gemm1

  cvt_kernel<<<3145728 / 256, 256, 0, stream>>>(x, Xb, 3145728);
  cvt_kernel<<<884736 / 256, 256, 0, stream>>>(w_qkv, Wq, 884736);
  cvt_kernel<<<589824 / 256, 256, 0, stream>>>(w_o, Wo, 589824);

  gemm3<288, ushort><<<256, 512, 0, stream>>>(Xb, Wq, QKV, 2304, 1536);

  rope_kernel<<<(8192 * 1344) / 256, 256, 0, stream>>>(QKV, Qr, Kr, Vt);

  attn2_kernel<<<256, 512, 0, stream>>>(Qr, Kr, Vt, pmask, Attn);

  gemm3<192, float><<<256, 512, 0, stream>>>(Attn, Wo, out, 1536, 1536);
}